// Round 6
// baseline (269.015 us; speedup 1.0000x reference)
//
#include <hip/hip_runtime.h>
#include <hip/hip_bf16.h>
#include <math.h>

#define BB   8
#define CC   80
#define HH   128
#define WW   128
#define HWN  16384
#define KTOP 100
#define NSTRIP 8
#define SR   16
#define LR   (SR + 4)
#define SCAP 512
#define CAPB 65536        // per-batch slab capacity; data ~52.4K (655/map * 80)
#define EPS  0.01f
#define EPSN 1e-3f        // sigma-safety radius: gap>=1e-3 -> sigma gap >= 14x fp noise

typedef unsigned long long ull;

__device__ __forceinline__ float sigmoidf_(float x) {
    // bitwise-matched vs jax.nn.sigmoid (R1/R3/R4)
    if (x >= 0.0f) return 1.0f / (1.0f + expf(-x));
    float e = expf(x);
    return e / (1.0f + e);
}

// value desc, class asc, hw asc; unique per (map,hw). Ordering == reference
// two-stage top-k (proof R2-R4, bitwise-validated).
__device__ __forceinline__ ull makekey(float v, int cls, int hw) {
    return ((ull)__float_as_uint(v) << 21)
         | ((ull)(127 - cls) << 14)
         | (ull)(16383 - hw);
}

__global__ void kzero(int* counts) {
    if (threadIdx.x < BB) counts[threadIdx.x] = 0;
}

// ---- Kernel A: logit-domain 5x5 peak NMS per 16-row strip, append candidates ----
__global__ __launch_bounds__(256) void knms(const float* __restrict__ logits,
                                            ull* __restrict__ slab,
                                            int* __restrict__ counts) {
    __shared__ __align__(16) float s[LR][WW];    // 10 KB raw logits (halo-clamped)
    __shared__ __align__(16) float m1[SR][WW];   // 8 KB vertical 5-max
    __shared__ ull cand[SCAP];                   // 4 KB
    __shared__ int cnt, gbase;

    const int tid   = threadIdx.x;
    const int map   = blockIdx.x >> 3;           // b*CC + c
    const int strip = blockIdx.x & 7;
    const int cls   = map % CC;
    const int b     = map / CC;
    const int R0    = strip * SR;
    const float* __restrict__ src = logits + (size_t)map * HWN;
    if (tid == 0) cnt = 0;

    // stage raw logits (no sigmoid), float4, halo rows clamped (== -inf pad for max)
    for (int v = tid; v < LR * 32; v += 256) {
        const int lr = v >> 5, c4 = (v & 31) << 2;
        int gr = R0 - 2 + lr;
        gr = gr < 0 ? 0 : (gr > HH - 1 ? HH - 1 : gr);
        *reinterpret_cast<float4*>(&s[lr][c4]) =
            *reinterpret_cast<const float4*>(src + (size_t)gr * WW + c4);
    }
    __syncthreads();

    // vertical 5-max per column, quad-vectorized
    for (int i = tid; i < SR * 32; i += 256) {
        const int r = i >> 5, c4 = (i & 31) << 2;
        const float4 r0 = *reinterpret_cast<const float4*>(&s[r][c4]);
        const float4 r1 = *reinterpret_cast<const float4*>(&s[r + 1][c4]);
        const float4 r2 = *reinterpret_cast<const float4*>(&s[r + 2][c4]);
        const float4 r3 = *reinterpret_cast<const float4*>(&s[r + 3][c4]);
        const float4 r4 = *reinterpret_cast<const float4*>(&s[r + 4][c4]);
        float4 m;
        m.x = fmaxf(fmaxf(r0.x, r1.x), fmaxf(fmaxf(r2.x, r3.x), r4.x));
        m.y = fmaxf(fmaxf(r0.y, r1.y), fmaxf(fmaxf(r2.y, r3.y), r4.y));
        m.z = fmaxf(fmaxf(r0.z, r1.z), fmaxf(fmaxf(r2.z, r3.z), r4.z));
        m.w = fmaxf(fmaxf(r0.w, r1.w), fmaxf(fmaxf(r2.w, r3.w), r4.w));
        *reinterpret_cast<float4*>(&m1[r][c4]) = m;
    }
    __syncthreads();

    // horizontal 5-max + keep decision (fast drop / robust near path)
    for (int i = tid; i < SR * 32; i += 256) {
        const int r = i >> 5, c4 = (i & 31) << 2;
        float w[12];
        if (c4 >= 4) {
            const float4 L = *reinterpret_cast<const float4*>(&m1[r][c4 - 4]);
            w[0] = L.x; w[1] = L.y; w[2] = L.z; w[3] = L.w;
        } else { w[0] = w[1] = w[2] = w[3] = -INFINITY; }
        {
            const float4 M = *reinterpret_cast<const float4*>(&m1[r][c4]);
            w[4] = M.x; w[5] = M.y; w[6] = M.z; w[7] = M.w;
        }
        if (c4 <= WW - 8) {
            const float4 R = *reinterpret_cast<const float4*>(&m1[r][c4 + 4]);
            w[8] = R.x; w[9] = R.y; w[10] = R.z; w[11] = R.w;
        } else { w[8] = w[9] = w[10] = w[11] = -INFINITY; }
        const float4 cen = *reinterpret_cast<const float4*>(&s[r + 2][c4]);
        const float cv[4] = {cen.x, cen.y, cen.z, cen.w};

#pragma unroll
        for (int j = 0; j < 4; ++j) {
            const float v = cv[j];
            const float M1 = fmaxf(fmaxf(w[2 + j], w[3 + j]),
                                   fmaxf(fmaxf(w[4 + j], w[5 + j]), w[6 + j]));
            bool keep;
            if (M1 - v > EPS) {
                keep = false;   // logit gap > EPS -> sigma strictly larger (>=600 ulp margin)
            } else {
                // near path (~4%): exact sigma max over cells that could possibly
                // reach sigma(v) under bounded fp error (x > v - EPSN); no
                // monotonicity assumption on fp sigmoid.
                const int gc = c4 + j;
                const float sv = sigmoidf_(v);
                float mx = sv;
                for (int rr = r; rr <= r + 4; ++rr) {
                    for (int dd = -2; dd <= 2; ++dd) {
                        int cc2 = gc + dd;
                        cc2 = cc2 < 0 ? 0 : (cc2 > 127 ? 127 : cc2);
                        const float x = s[rr][cc2];
                        if (x > v - EPSN && x != v)
                            mx = fmaxf(mx, sigmoidf_(x));
                    }
                }
                keep = (mx == sv);   // == reference hmax == cls
            }
            if (keep) {
                const int slot = atomicAdd(&cnt, 1);
                if (slot < SCAP)
                    cand[slot] = makekey(sigmoidf_(v), cls, ((R0 + r) << 7) | (c4 + j));
            }
        }
    }
    __syncthreads();

    const int n = cnt < SCAP ? cnt : SCAP;
    if (tid == 0) gbase = atomicAdd(counts + b, n);
    __syncthreads();
    const int gb = gbase;
    for (int i = tid; i < n; i += 256) {
        const int gi = gb + i;
        if (gi < CAPB) slab[(size_t)b * CAPB + gi] = cand[i];
    }
}

// ---- in-register wave bitonic helpers (64 lanes) ----
__device__ __forceinline__ ull sort64_desc(ull v, int lane) {
    for (int k = 2; k <= 64; k <<= 1) {
        for (int j = k >> 1; j >= 1; j >>= 1) {
            const ull p = __shfl_xor(v, j, 64);
            const bool km = (((lane & k) == 0) != ((lane & j) != 0));
            v = (km == (p > v)) ? p : v;
        }
    }
    return v;
}

__device__ __forceinline__ void bmerge128(ull& a0, ull& a1, int lane) {
    // [a0;a1] bitonic -> sorted desc
    const ull t0 = a0 > a1 ? a0 : a1;
    a1 = a0 > a1 ? a1 : a0;
    a0 = t0;
    for (int j = 32; j >= 1; j >>= 1) {
        const ull p0 = __shfl_xor(a0, j, 64);
        const ull p1 = __shfl_xor(a1, j, 64);
        const bool km = ((lane & j) == 0);
        a0 = (km == (p0 > a0)) ? p0 : a0;
        a1 = (km == (p1 > a1)) ? p1 : a1;
    }
}

// ---- Kernel B: per-batch streaming top-128 + tree merge + decode ----
__global__ __launch_bounds__(1024) void ktail(const ull* __restrict__ slab,
                                              const int* __restrict__ counts,
                                              const float* __restrict__ txty,
                                              const float* __restrict__ twth,
                                              float* __restrict__ out) {
    __shared__ ull lists[16][128];               // 16 KB
    const int tid = threadIdx.x, b = blockIdx.x;
    const int w = tid >> 6, lane = tid & 63;

    int n = counts[b];
    n = n < CAPB ? n : CAPB;
    const ull* __restrict__ base = slab + (size_t)b * CAPB;

    // phase 1: each wave streams chunks of 64 -> running sorted-128 (regs, no barriers)
    ull a0 = 0ULL, a1 = 0ULL;
    for (int c = w; c * 64 < n; c += 16) {
        const int idx = c * 64 + lane;
        ull v = (idx < n) ? base[idx] : 0ULL;
        v = sort64_desc(v, lane);
        const ull rv = __shfl(v, 63 - lane, 64);   // reversed chunk (ascending)
        a1 = a1 > rv ? a1 : rv;                    // valley vs bottom half
        bmerge128(a0, a1, lane);
    }
    lists[w][lane] = a0;
    lists[w][64 + lane] = a1;

    // phase 2: tree merge 16 -> 1 (top-128 kept each round)
    for (int half = 8; half >= 1; half >>= 1) {
        __syncthreads();
        ull z0 = 0ULL, z1 = 0ULL;
        const bool act = (w < half);
        if (act) {
            const ull l0 = lists[2 * w][lane];
            const ull l1 = lists[2 * w][64 + lane];
            const ull r1r = lists[2 * w + 1][127 - lane];
            const ull r0r = lists[2 * w + 1][63 - lane];
            z0 = l0 > r1r ? l0 : r1r;
            z1 = l1 > r0r ? l1 : r0r;
            bmerge128(z0, z1, lane);
        }
        __syncthreads();
        if (act) { lists[w][lane] = z0; lists[w][64 + lane] = z1; }
    }
    __syncthreads();

    // phase 3: outputs + fused box decode
    if (tid < KTOP) {
        const ull key = lists[0][tid];
        const int hw  = 16383 - (int)(key & 0x3FFFULL);
        const int cls = 127 - (int)((key >> 14) & 0x7FULL);
        const float sc = __uint_as_float((unsigned int)(key >> 21));

        // out layout (float32): score[0..800) | bbox[800..4000) | inds[4000..4800) | clses[4800..5600)
        out[b * KTOP + tid]        = sc;
        out[4000 + b * KTOP + tid] = (float)hw;
        out[4800 + b * KTOP + tid] = (float)cls;

        const int xx = hw & 127, yy = hw >> 7;
        const float* __restrict__ t = txty + (size_t)b * 2 * HWN;
        const float* __restrict__ u = twth + (size_t)b * 2 * HWN;
        const float tx = t[hw], ty = t[HWN + hw];
        const float tw = u[hw], th = u[HWN + hw];

        const float cx = (sigmoidf_(tx) + (float)xx) * 4.0f;
        const float cy = (sigmoidf_(ty) + (float)yy) * 4.0f;
        const float bw = expf(tw) * 4.0f;
        const float bh = expf(th) * 4.0f;

        const float inv = 1.0f / 512.0f;
        float x1 = (cx - bw * 0.5f) * inv;
        float y1 = (cy - bh * 0.5f) * inv;
        float x2 = (cx + bw * 0.5f) * inv;
        float y2 = (cy + bh * 0.5f) * inv;
        x1 = fminf(fmaxf(x1, 0.0f), 1.0f);
        y1 = fminf(fmaxf(y1, 0.0f), 1.0f);
        x2 = fminf(fmaxf(x2, 0.0f), 1.0f);
        y2 = fminf(fmaxf(y2, 0.0f), 1.0f);

        float* bb = out + 800 + (size_t)(b * KTOP + tid) * 4;
        bb[0] = x1; bb[1] = y1; bb[2] = x2; bb[3] = y2;
    }
}

extern "C" void kernel_launch(void* const* d_in, const int* in_sizes, int n_in,
                              void* d_out, int out_size, void* d_ws, size_t ws_size,
                              hipStream_t stream) {
    const float* cls_logits = (const float*)d_in[0];
    const float* txty       = (const float*)d_in[1];
    const float* twth       = (const float*)d_in[2];
    float* out = (float*)d_out;

    // ws: slab 8*65536*8 = 4,194,304 B | counts 8*4 B
    ull* slab   = (ull*)d_ws;
    int* counts = (int*)((char*)d_ws + (size_t)BB * CAPB * 8);

    kzero<<<1, 64, 0, stream>>>(counts);
    knms <<<BB * CC * NSTRIP, 256, 0, stream>>>(cls_logits, slab, counts);
    ktail<<<BB, 1024, 0, stream>>>(slab, counts, txty, twth, out);
}

// Round 7
// 96.822 us; speedup vs baseline: 2.7784x; 2.7784x over previous
//
#include <hip/hip_runtime.h>
#include <hip/hip_bf16.h>
#include <math.h>

#define BB   8
#define CC   80
#define HH   128
#define WW   128
#define HWN  16384
#define KTOP 100
#define NSTRIP 8
#define SR   16
#define LR   (SR + 4)
#define SCAP 512
#define CAPB 65536          // per-batch slab capacity; real data ~52.4K (R6-validated)
#define NSEG 64             // kred segments per batch; NSEG*1024 == CAPB

typedef unsigned long long ull;

__device__ __forceinline__ float sigmoidf_(float x) {
    // bitwise-matched vs jax.nn.sigmoid (R1/R3/R4/R6)
    if (x >= 0.0f) return 1.0f / (1.0f + expf(-x));
    float e = expf(x);
    return e / (1.0f + e);
}

// value desc, class asc, hw asc; unique per (map,hw). Ordering == reference
// two-stage top-k (proof R2-R4, bitwise-validated through R6).
__device__ __forceinline__ ull makekey(float v, int cls, int hw) {
    return ((ull)__float_as_uint(v) << 21)
         | ((ull)(127 - cls) << 14)
         | (ull)(16383 - hw);
}

// ---- Kernel A: sigmoid + fused 5x5 peak NMS per 16-row strip, append keys ----
__global__ __launch_bounds__(256, 8) void knms(const float* __restrict__ logits,
                                               ull* __restrict__ slab,
                                               int* __restrict__ counts) {
    __shared__ __align__(16) float s[LR][WW];    // 10 KB sigmoid tile (halo-clamped)
    __shared__ ull cand[SCAP];                   // 4 KB
    __shared__ int cnt, gbase;

    const int tid   = threadIdx.x;
    const int map   = blockIdx.x >> 3;           // b*CC + c
    const int strip = blockIdx.x & 7;
    const int cls   = map % CC;
    const int b     = map / CC;
    const int R0    = strip * SR;
    const float* __restrict__ src = logits + (size_t)map * HWN;
    if (tid == 0) cnt = 0;

    // stage: 640 quads; 3 independent loads issued up front (MLP), then sigmoid
    {
        const int v0 = tid, v1 = tid + 256, v2 = tid + 512;
        int gr0 = R0 - 2 + (v0 >> 5); gr0 = gr0 < 0 ? 0 : (gr0 > 127 ? 127 : gr0);
        int gr1 = R0 - 2 + (v1 >> 5); gr1 = gr1 < 0 ? 0 : (gr1 > 127 ? 127 : gr1);
        int gr2 = R0 - 2 + (v2 >> 5); gr2 = gr2 < 0 ? 0 : (gr2 > 127 ? 127 : gr2);
        const int c0 = (v0 & 31) << 2, c1 = (v1 & 31) << 2, c2 = (v2 & 31) << 2;
        const float4 f0 = *reinterpret_cast<const float4*>(src + (size_t)gr0 * WW + c0);
        const float4 f1 = *reinterpret_cast<const float4*>(src + (size_t)gr1 * WW + c1);
        float4 f2;
        if (tid < 128) f2 = *reinterpret_cast<const float4*>(src + (size_t)gr2 * WW + c2);
        float4 o;
        o.x = sigmoidf_(f0.x); o.y = sigmoidf_(f0.y); o.z = sigmoidf_(f0.z); o.w = sigmoidf_(f0.w);
        *reinterpret_cast<float4*>(&s[v0 >> 5][c0]) = o;
        o.x = sigmoidf_(f1.x); o.y = sigmoidf_(f1.y); o.z = sigmoidf_(f1.z); o.w = sigmoidf_(f1.w);
        *reinterpret_cast<float4*>(&s[v1 >> 5][c1]) = o;
        if (tid < 128) {
            o.x = sigmoidf_(f2.x); o.y = sigmoidf_(f2.y); o.z = sigmoidf_(f2.z); o.w = sigmoidf_(f2.w);
            *reinterpret_cast<float4*>(&s[v2 >> 5][c2]) = o;
        }
    }
    __syncthreads();

    // fused 5x5 window max per center quad (registers only), keep, compact
    for (int i = tid; i < SR * 32; i += 256) {
        const int r = i >> 5, c4 = (i & 31) << 2;
        const bool hasL = (c4 >= 4), hasR = (c4 <= WW - 8);
        float wv[12];
#pragma unroll
        for (int k = 0; k < 12; ++k) wv[k] = -INFINITY;
#pragma unroll
        for (int rr = 0; rr < 5; ++rr) {
            const float4 C = *reinterpret_cast<const float4*>(&s[r + rr][c4]);
            wv[4] = fmaxf(wv[4], C.x); wv[5] = fmaxf(wv[5], C.y);
            wv[6] = fmaxf(wv[6], C.z); wv[7] = fmaxf(wv[7], C.w);
            if (hasL) {
                const float4 L = *reinterpret_cast<const float4*>(&s[r + rr][c4 - 4]);
                wv[0] = fmaxf(wv[0], L.x); wv[1] = fmaxf(wv[1], L.y);
                wv[2] = fmaxf(wv[2], L.z); wv[3] = fmaxf(wv[3], L.w);
            }
            if (hasR) {
                const float4 R = *reinterpret_cast<const float4*>(&s[r + rr][c4 + 4]);
                wv[8] = fmaxf(wv[8], R.x); wv[9] = fmaxf(wv[9], R.y);
                wv[10] = fmaxf(wv[10], R.z); wv[11] = fmaxf(wv[11], R.w);
            }
        }
        const float4 cen = *reinterpret_cast<const float4*>(&s[r + 2][c4]);
        const float cv[4] = {cen.x, cen.y, cen.z, cen.w};
#pragma unroll
        for (int j = 0; j < 4; ++j) {
            const float m = fmaxf(fmaxf(wv[2 + j], wv[3 + j]),
                                  fmaxf(fmaxf(wv[4 + j], wv[5 + j]), wv[6 + j]));
            if (cv[j] == m) {          // exact reference keep: sigma == 5x5 sigma-max
                const int slot = atomicAdd(&cnt, 1);
                if (slot < SCAP)
                    cand[slot] = makekey(cv[j], cls, ((R0 + r) << 7) | (c4 + j));
            }
        }
    }
    __syncthreads();

    const int n = cnt < SCAP ? cnt : SCAP;
    if (tid == 0) gbase = atomicAdd(counts + b, n);
    __syncthreads();
    const int gb = gbase;
    for (int i = tid; i < n; i += 256) {
        const int gi = gb + i;
        if (gi < CAPB) slab[(size_t)b * CAPB + gi] = cand[i];
    }
}

// ---- in-register wave bitonic helpers (64 lanes; R6-validated) ----
__device__ __forceinline__ ull sort64_desc(ull v, int lane) {
    for (int k = 2; k <= 64; k <<= 1) {
        for (int j = k >> 1; j >= 1; j >>= 1) {
            const ull p = __shfl_xor(v, j, 64);
            const bool km = (((lane & k) == 0) != ((lane & j) != 0));
            v = (km == (p > v)) ? p : v;
        }
    }
    return v;
}

__device__ __forceinline__ void bmerge128(ull& a0, ull& a1, int lane) {
    const ull t0 = a0 > a1 ? a0 : a1;
    a1 = a0 > a1 ? a1 : a0;
    a0 = t0;
    for (int j = 32; j >= 1; j >>= 1) {
        const ull p0 = __shfl_xor(a0, j, 64);
        const ull p1 = __shfl_xor(a1, j, 64);
        const bool km = ((lane & j) == 0);
        a0 = (km == (p0 > a0)) ? p0 : a0;
        a1 = (km == (p1 > a1)) ? p1 : a1;
    }
}

// ---- Kernel B: distributed reduce — per 1024-key segment -> sorted top-128 ----
__global__ __launch_bounds__(256) void kred(const ull* __restrict__ slab,
                                            const int* __restrict__ counts,
                                            ull* __restrict__ lists) {
    __shared__ ull ls[4][128];
    const int tid = threadIdx.x, w = tid >> 6, lane = tid & 63;
    const int b = blockIdx.x >> 6, seg = blockIdx.x & (NSEG - 1);

    int n = counts[b];
    n = n < CAPB ? n : CAPB;
    int avail = n - seg * 1024;
    avail = avail < 0 ? 0 : (avail > 1024 ? 1024 : avail);
    const ull* __restrict__ base = slab + (size_t)b * CAPB + seg * 1024;

    // each wave: 4 chunks of 64 -> running sorted-128 in regs (no barriers)
    ull a0 = 0ULL, a1 = 0ULL;
#pragma unroll
    for (int c = 0; c < 4; ++c) {
        const int idx = (w * 4 + c) * 64 + lane;
        ull v = (idx < avail) ? base[idx] : 0ULL;
        v = sort64_desc(v, lane);
        const ull rv = __shfl(v, 63 - lane, 64);
        a1 = a1 > rv ? a1 : rv;
        bmerge128(a0, a1, lane);
    }
    ls[w][lane] = a0;
    ls[w][64 + lane] = a1;

    // merge 4 wave lists -> 1 (two rounds)
    for (int half = 2; half >= 1; half >>= 1) {
        __syncthreads();
        ull z0 = 0ULL, z1 = 0ULL;
        const bool act = (w < half);
        if (act) {
            const ull l0 = ls[2 * w][lane];
            const ull l1 = ls[2 * w][64 + lane];
            const ull r1r = ls[2 * w + 1][127 - lane];
            const ull r0r = ls[2 * w + 1][63 - lane];
            z0 = l0 > r1r ? l0 : r1r;
            z1 = l1 > r0r ? l1 : r0r;
            bmerge128(z0, z1, lane);
        }
        __syncthreads();
        if (act) { ls[w][lane] = z0; ls[w][64 + lane] = z1; }
    }
    __syncthreads();
    for (int i = tid; i < 128; i += 256)
        lists[(size_t)blockIdx.x * 128 + i] = ls[0][i];
    if (tid >= 128 && tid < 256) { /* no-op */ }
    if (tid < 128) { } // (store handled above; single iteration)
}

// ---- Kernel C: per-batch tree merge of 64 sorted lists + decode ----
__global__ __launch_bounds__(1024) void ktail(const ull* __restrict__ lists,
                                              const float* __restrict__ txty,
                                              const float* __restrict__ twth,
                                              float* __restrict__ out) {
    __shared__ ull ch[NSEG][128];                // 64 KB
    const int tid = threadIdx.x, b = blockIdx.x;

    for (int t = tid; t < NSEG * 128; t += 1024)
        ch[t >> 7][t & 127] = lists[(size_t)b * NSEG * 128 + t];
    __syncthreads();

    // tournament: 64 -> 1, keep top-128 each round (R4-validated valley+merge)
    int nch = NSEG;
    while (nch > 1) {
        const int newn  = (nch + 1) >> 1;
        const int npair = nch - newn;
        for (int t = tid; t < npair * 128; t += 1024) {
            const int p = t >> 7, i = t & 127;
            ull a = ch[p][i], bv = ch[p + newn][127 - i];
            if (a < bv) { ch[p][i] = bv; ch[p + newn][127 - i] = a; }
        }
        __syncthreads();
        for (int j = 64; j >= 1; j >>= 1) {
            for (int t = tid; t < npair * 64; t += 1024) {
                const int p = t >> 6, q = t & 63;
                const int i = ((q & ~(j - 1)) << 1) | (q & (j - 1));
                ull a = ch[p][i], bv = ch[p][i | j];
                if (a < bv) { ch[p][i] = bv; ch[p][i | j] = a; }
            }
            __syncthreads();
        }
        nch = newn;
    }

    if (tid < KTOP) {
        const ull key = ch[0][tid];
        const int hw  = 16383 - (int)(key & 0x3FFFULL);
        const int cls = 127 - (int)((key >> 14) & 0x7FULL);
        const float sc = __uint_as_float((unsigned int)(key >> 21));

        // out layout (float32): score[0..800) | bbox[800..4000) | inds[4000..4800) | clses[4800..5600)
        out[b * KTOP + tid]        = sc;
        out[4000 + b * KTOP + tid] = (float)hw;
        out[4800 + b * KTOP + tid] = (float)cls;

        const int xx = hw & 127, yy = hw >> 7;
        const float* __restrict__ t = txty + (size_t)b * 2 * HWN;
        const float* __restrict__ u = twth + (size_t)b * 2 * HWN;
        const float tx = t[hw], ty = t[HWN + hw];
        const float tw = u[hw], th = u[HWN + hw];

        const float cx = (sigmoidf_(tx) + (float)xx) * 4.0f;
        const float cy = (sigmoidf_(ty) + (float)yy) * 4.0f;
        const float bw = expf(tw) * 4.0f;
        const float bh = expf(th) * 4.0f;

        const float inv = 1.0f / 512.0f;
        float x1 = (cx - bw * 0.5f) * inv;
        float y1 = (cy - bh * 0.5f) * inv;
        float x2 = (cx + bw * 0.5f) * inv;
        float y2 = (cy + bh * 0.5f) * inv;
        x1 = fminf(fmaxf(x1, 0.0f), 1.0f);
        y1 = fminf(fmaxf(y1, 0.0f), 1.0f);
        x2 = fminf(fmaxf(x2, 0.0f), 1.0f);
        y2 = fminf(fmaxf(y2, 0.0f), 1.0f);

        float* bb = out + 800 + (size_t)(b * KTOP + tid) * 4;
        bb[0] = x1; bb[1] = y1; bb[2] = x2; bb[3] = y2;
    }
}

extern "C" void kernel_launch(void* const* d_in, const int* in_sizes, int n_in,
                              void* d_out, int out_size, void* d_ws, size_t ws_size,
                              hipStream_t stream) {
    const float* cls_logits = (const float*)d_in[0];
    const float* txty       = (const float*)d_in[1];
    const float* twth       = (const float*)d_in[2];
    float* out = (float*)d_out;

    // ws: slab 8*65536*8 = 4,194,304 | counts 32 B | lists 512*128*8 = 524,288
    ull* slab   = (ull*)d_ws;
    int* counts = (int*)((char*)d_ws + (size_t)BB * CAPB * 8);
    ull* lists  = (ull*)((char*)d_ws + (size_t)BB * CAPB * 8 + 256);

    hipMemsetAsync(counts, 0, BB * sizeof(int), stream);
    knms <<<BB * CC * NSTRIP, 256, 0, stream>>>(cls_logits, slab, counts);
    kred <<<BB * NSEG,        256, 0, stream>>>(slab, counts, lists);
    ktail<<<BB,              1024, 0, stream>>>(lists, txty, twth, out);
}